// Round 1
// baseline (23647.969 us; speedup 1.0000x reference)
//
#include <hip/hip_runtime.h>
#include <math.h>

// Problem constants
constexpr int B = 64, T = 128, D = 512, L = 9, S = 64;
constexpr int G = 4 * D;  // 2048 gate columns

// ---------------------------------------------------------------------------
// K1: embedding gather.  h stored [T][D][B] (lane = batch => coalesced writes)
// grid = T*8 blocks (t, 64-wide d-chunk), block = 256
// ---------------------------------------------------------------------------
__global__ __launch_bounds__(256) void k_embed(const int* __restrict__ x,
                                               const float* __restrict__ emb,
                                               float* __restrict__ h) {
    int t  = blockIdx.x >> 3;
    int c0 = (blockIdx.x & 7) * 64;
    int r  = threadIdx.x & 63;   // batch
    int q  = threadIdx.x >> 6;   // 0..3
    int xi = x[r * T + t];
    const float* erow = emb + (size_t)xi * D + c0 + q * 16;
    float* out = h + ((size_t)t * D + c0 + q * 16) * B + r;
#pragma unroll
    for (int j = 0; j < 16; j++) out[(size_t)j * B] = erow[j];
}

// ---------------------------------------------------------------------------
// K2: input projection  xg[t][n][b] = sum_k h[t][k][b] * W[n][k] + bias[n]
// A is column-major per t-slice ([D][B]).  Tile 64b x 64n, BK=32, 256 thr.
// grid = (G/64, T)
// ---------------------------------------------------------------------------
__global__ __launch_bounds__(256) void k_xg(const float* __restrict__ h,
                                            const float* __restrict__ W,
                                            const float* __restrict__ bias,
                                            float* __restrict__ xg) {
    int t  = blockIdx.y;
    int n0 = blockIdx.x * 64;
    int tid = threadIdx.x;
    int tx = tid & 15, ty = tid >> 4;  // tx: n-sub, ty: b-sub

    __shared__ float As[32][68];  // [k][b]
    __shared__ float Bs[32][68];  // [k][n]
    float acc[4][4] = {};         // [b][n]

    const float* hA = h + (size_t)t * D * B;  // [D][B]

    for (int k0 = 0; k0 < D; k0 += 32) {
        // A tile: 32 k-rows x 64 b, coalesced float4 along b
        {
            int kk = tid >> 4, f4 = tid & 15;
            float4 a0 = *((const float4*)(hA + (size_t)(k0 + kk) * B) + f4);
            *(float4*)&As[kk][f4 * 4] = a0;
            float4 a1 = *((const float4*)(hA + (size_t)(k0 + kk + 16) * B) + f4);
            *(float4*)&As[kk + 16][f4 * 4] = a1;
        }
        // W tile: rows n0..n0+63, k0..k0+31, transposed into Bs[k][n]
        {
            int nn = tid >> 3, f4k = tid & 7;
#pragma unroll
            for (int h2 = 0; h2 < 2; h2++) {
                int n = nn + h2 * 32;
                float4 w = *((const float4*)(W + (size_t)(n0 + n) * D + k0) + f4k);
                Bs[f4k * 4 + 0][n] = w.x;
                Bs[f4k * 4 + 1][n] = w.y;
                Bs[f4k * 4 + 2][n] = w.z;
                Bs[f4k * 4 + 3][n] = w.w;
            }
        }
        __syncthreads();
#pragma unroll
        for (int k = 0; k < 32; k++) {
            float4 a  = *(float4*)&As[k][ty * 4];
            float4 bb = *(float4*)&Bs[k][tx * 4];
            float av[4] = {a.x, a.y, a.z, a.w};
            float bv[4] = {bb.x, bb.y, bb.z, bb.w};
#pragma unroll
            for (int i = 0; i < 4; i++)
#pragma unroll
                for (int j = 0; j < 4; j++) acc[i][j] = fmaf(av[i], bv[j], acc[i][j]);
        }
        __syncthreads();
    }
    // store xg[t][n][b] (+bias), float4 over b
    float* out = xg + ((size_t)t * G + n0) * B;
#pragma unroll
    for (int j = 0; j < 4; j++) {
        int n = tx * 4 + j;
        float bn = bias[n0 + n];
        float4 v;
        v.x = acc[0][j] + bn;
        v.y = acc[1][j] + bn;
        v.z = acc[2][j] + bn;
        v.w = acc[3][j] + bn;
        *(float4*)(out + (size_t)n * B + ty * 4) = v;
    }
}

// ---------------------------------------------------------------------------
// K3: one LSTM time step.
// gates[b][n] = xg[t][n][b] + sum_k h[t-1][k][b] * Whh[n][k]
// grid = D/2 = 256 blocks (2 d-values each), block = 256.
// thread: r = batch lane, hi = wave id: dsel = hi>>1 (which d), gp = hi&1
//   gp==0 computes gates i,f ; gp==1 computes gates g,o ; LDS exchange.
// Whh rows are wave-uniform -> readfirstlane -> scalar loads.
// ---------------------------------------------------------------------------
__global__ __launch_bounds__(256) void k_step(const float* __restrict__ xg,
                                              const float* __restrict__ Whh,
                                              float* __restrict__ h,
                                              float* __restrict__ c, int t) {
    int tid = threadIdx.x;
    int r   = tid & 63;
    int hi  = tid >> 6;            // wave id 0..3 (uniform per wave)
    int dsel = hi >> 1;            // 0..1
    int gp   = hi & 1;             // 0: gates i,f   1: gates g,o
    int dd   = blockIdx.x * 2 + dsel;
    int g0   = gp * 2;

    int dd_u = __builtin_amdgcn_readfirstlane(dd);
    int g0_u = __builtin_amdgcn_readfirstlane(g0);

    const float* W0 = Whh + ((size_t)g0_u * D + dd_u) * D;
    const float* W1 = Whh + ((size_t)(g0_u + 1) * D + dd_u) * D;
    const float* xgt = xg + (size_t)t * G * B;

    float acc0 = xgt[((size_t)g0_u * D + dd_u) * B + r];
    float acc1 = xgt[((size_t)(g0_u + 1) * D + dd_u) * B + r];

    if (t > 0) {
        const float* hp = h + (size_t)(t - 1) * D * B + r;
#pragma unroll 8
        for (int k = 0; k < D; k++) {
            float hk = hp[(size_t)k * B];
            acc0 = fmaf(hk, W0[k], acc0);
            acc1 = fmaf(hk, W1[k], acc1);
        }
    }

    __shared__ float ex[2][2][64];
    if (gp == 1) {
        ex[dsel][0][r] = acc0;  // gate g
        ex[dsel][1][r] = acc1;  // gate o
    }
    __syncthreads();
    if (gp == 0) {
        float gi = acc0, gf = acc1;
        float gg = ex[dsel][0][r];
        float go = ex[dsel][1][r];
        float co = (t > 0) ? c[(size_t)dd_u * B + r] : 0.f;
        float si = 1.f / (1.f + __expf(-gi));
        float sf = 1.f / (1.f + __expf(-gf));
        float so = 1.f / (1.f + __expf(-go));
        float tg = tanhf(gg);
        float cn = fmaf(sf, co, si * tg);
        c[(size_t)dd_u * B + r] = cn;
        h[((size_t)t * D + dd_u) * B + r] = so * tanhf(cn);
    }
}

// ---------------------------------------------------------------------------
// K4: LayerNorm over D for each (b,t); h is [T][D][B]; hn out is [B][T][D].
// grid = T, block = 256.  Transpose through LDS for coalesced writes.
// ---------------------------------------------------------------------------
__global__ __launch_bounds__(256) void k_ln(const float* __restrict__ h,
                                            const float* __restrict__ gamma,
                                            const float* __restrict__ beta,
                                            float* __restrict__ hn) {
    int t = blockIdx.x;
    int r = threadIdx.x & 63;
    int q = threadIdx.x >> 6;
    const float* ht = h + (size_t)t * D * B;

    __shared__ float red[4][2][64];
    __shared__ float mr[2][64];
    __shared__ float tile[64][65];

    float s1 = 0.f, s2 = 0.f;
    for (int dd = q * 128; dd < q * 128 + 128; dd++) {
        float v = ht[(size_t)dd * B + r];
        s1 += v;
        s2 = fmaf(v, v, s2);
    }
    red[q][0][r] = s1;
    red[q][1][r] = s2;
    __syncthreads();
    if (q == 0) {
        float a = 0.f, b2 = 0.f;
#pragma unroll
        for (int i = 0; i < 4; i++) {
            a += red[i][0][r];
            b2 += red[i][1][r];
        }
        float mean = a / D;
        float var  = b2 / D - mean * mean;
        mr[0][r] = mean;
        mr[1][r] = rsqrtf(var + 1e-5f);
    }
    __syncthreads();

    for (int c0 = 0; c0 < D; c0 += 64) {
#pragma unroll
        for (int j = 0; j < 16; j++) {
            int dl = q * 16 + j;
            int dd = c0 + dl;
            float v = ht[(size_t)dd * B + r];
            v = fmaf((v - mr[0][r]) * mr[1][r], gamma[dd], beta[dd]);
            tile[r][dl] = v;
        }
        __syncthreads();
#pragma unroll
        for (int j = 0; j < 16; j++) {
            int rl = q * 16 + j;  // batch row
            hn[((size_t)rl * T + t) * D + c0 + r] = tile[rl][r];
        }
        __syncthreads();
    }
}

// ---------------------------------------------------------------------------
// K5: head GEMM  logits[m][s] = sum_k hn[m][k]*head_W[s][k] + head_b[s]
// hn row-major [8192][512]; tile 64m x 64s, BK=32. grid = 8192/64 = 128.
// ---------------------------------------------------------------------------
__global__ __launch_bounds__(256) void k_head(const float* __restrict__ hn,
                                              const float* __restrict__ hw,
                                              const float* __restrict__ hb,
                                              float* __restrict__ out) {
    int m0 = blockIdx.x * 64;
    int tid = threadIdx.x;
    int tx = tid & 15, ty = tid >> 4;  // tx: s-sub, ty: m-sub

    __shared__ float As[32][68];  // [k][m]
    __shared__ float Bs[32][68];  // [k][s]
    float acc[4][4] = {};         // [m][s]

    for (int k0 = 0; k0 < D; k0 += 32) {
        int mm = tid >> 3, f4k = tid & 7;
#pragma unroll
        for (int h2 = 0; h2 < 2; h2++) {
            int m = mm + h2 * 32;
            float4 a = *((const float4*)(hn + (size_t)(m0 + m) * D + k0) + f4k);
            As[f4k * 4 + 0][m] = a.x;
            As[f4k * 4 + 1][m] = a.y;
            As[f4k * 4 + 2][m] = a.z;
            As[f4k * 4 + 3][m] = a.w;
            float4 w = *((const float4*)(hw + (size_t)m * D + k0) + f4k);  // m doubles as s row
            Bs[f4k * 4 + 0][m] = w.x;
            Bs[f4k * 4 + 1][m] = w.y;
            Bs[f4k * 4 + 2][m] = w.z;
            Bs[f4k * 4 + 3][m] = w.w;
        }
        __syncthreads();
#pragma unroll
        for (int k = 0; k < 32; k++) {
            float4 a  = *(float4*)&As[k][ty * 4];
            float4 bb = *(float4*)&Bs[k][tx * 4];
            float av[4] = {a.x, a.y, a.z, a.w};
            float bv[4] = {bb.x, bb.y, bb.z, bb.w};
#pragma unroll
            for (int i = 0; i < 4; i++)
#pragma unroll
                for (int j = 0; j < 4; j++) acc[i][j] = fmaf(av[i], bv[j], acc[i][j]);
        }
        __syncthreads();
    }
    float* o = out + (size_t)m0 * S;
#pragma unroll
    for (int i = 0; i < 4; i++) {
        int m = ty * 4 + i;
        float4 v;
        v.x = acc[i][0] + hb[tx * 4 + 0];
        v.y = acc[i][1] + hb[tx * 4 + 1];
        v.z = acc[i][2] + hb[tx * 4 + 2];
        v.w = acc[i][3] + hb[tx * 4 + 3];
        *(float4*)(o + (size_t)m * S + tx * 4) = v;
    }
}

// ---------------------------------------------------------------------------
extern "C" void kernel_launch(void* const* d_in, const int* in_sizes, int n_in,
                              void* d_out, int out_size, void* d_ws, size_t ws_size,
                              hipStream_t stream) {
    const int*   x      = (const int*)d_in[0];
    const float* emb    = (const float*)d_in[1];
    const float* W_ih   = (const float*)d_in[2];
    const float* W_hh   = (const float*)d_in[3];
    const float* bvec   = (const float*)d_in[4];
    const float* gamma  = (const float*)d_in[5];
    const float* beta   = (const float*)d_in[6];
    const float* head_W = (const float*)d_in[7];
    const float* head_b = (const float*)d_in[8];

    float* logits = (float*)d_out;                    // [B,T,S]
    float* hn     = (float*)d_out + (size_t)B * T * S;  // [B,T,D]

    float* h  = (float*)d_ws;                         // [T][D][B]
    float* xg = h + (size_t)T * D * B;                // [T][G][B]
    float* c  = xg + (size_t)T * G * B;               // [D][B]

    k_embed<<<dim3(T * 8), 256, 0, stream>>>(x, emb, h);
    for (int l = 0; l < L; l++) {
        k_xg<<<dim3(G / 64, T), 256, 0, stream>>>(h, W_ih + (size_t)l * G * D,
                                                  bvec + (size_t)l * G, xg);
        for (int t = 0; t < T; t++) {
            k_step<<<dim3(D / 2), 256, 0, stream>>>(xg, W_hh + (size_t)l * G * D, h, c, t);
        }
    }
    k_ln<<<dim3(T), 256, 0, stream>>>(h, gamma, beta, hn);
    k_head<<<dim3(B * T / 64), 256, 0, stream>>>(hn, head_W, head_b, logits);
}

// Round 2
// 8056.981 us; speedup vs baseline: 2.9351x; 2.9351x over previous
//
#include <hip/hip_runtime.h>
#include <math.h>

// Problem constants
constexpr int B = 64, T = 128, D = 512, L = 9, S = 64;
constexpr int G = 4 * D;  // 2048 gate rows per layer

// ---------------------------------------------------------------------------
// K1: embedding gather.  hemb stored [T][D][B] (lane = batch => coalesced)
// grid = T*8 blocks (t, 64-wide d-chunk), block = 256
// ---------------------------------------------------------------------------
__global__ __launch_bounds__(256) void k_embed(const int* __restrict__ x,
                                               const float* __restrict__ emb,
                                               float* __restrict__ hemb) {
    int t  = blockIdx.x >> 3;
    int c0 = (blockIdx.x & 7) * 64;
    int r  = threadIdx.x & 63;   // batch
    int q  = threadIdx.x >> 6;   // 0..3
    int xi = x[r * T + t];
    const float* erow = emb + (size_t)xi * D + c0 + q * 16;
    float* out = hemb + ((size_t)t * D + c0 + q * 16) * B + r;
#pragma unroll
    for (int j = 0; j < 16; j++) out[(size_t)j * B] = erow[j];
}

// ---------------------------------------------------------------------------
// K2: one wavefront-diagonal of LSTM cells.
// Cell (l, t) with l + t == d.  gates[n][b] = bias[n]
//        + sum_k h_below[k][b] * W_ih[n][k]  + sum_k h_prev[k][b] * W_hh[n][k]
// Block: 32 blocks per cell; block bt covers d-values [bt*16, bt*16+16) x all
// 4 gates (64 weight rows) x all 64 batches.  256 threads:
//   tx = tid & 15  -> d-sub (one d per tx)
//   ty = tid >> 4  -> b-sub (4 batches per thread)
// Row index rr = tx*4 + j maps to (gate = rr & 3, dsub = rr >> 2 = tx), so each
// thread holds ALL FOUR gates for its (d, b) pairs -> local cell update.
// State ping-pong by diagonal parity: reads from parity p^1, writes parity p.
// Layer 8 output goes to hfinal[t] (full history, feeds LN).
// ---------------------------------------------------------------------------
__global__ __launch_bounds__(256) void k_cell(const float* __restrict__ hemb,
                                              float* __restrict__ hfinal,
                                              float* __restrict__ hpp,   // [2][8][D][B]
                                              float* __restrict__ cpp,   // [2][9][D][B]
                                              const float* __restrict__ W_ih,
                                              const float* __restrict__ W_hh,
                                              const float* __restrict__ bias,
                                              int d) {
    const int lmin = (d > T - 1) ? (d - (T - 1)) : 0;
    const int ci = blockIdx.x >> 5;
    const int bt = blockIdx.x & 31;
    const int l  = lmin + ci;
    const int t  = d - l;
    const int p  = d & 1;

    const int d0 = bt * 16;
    const int tid = threadIdx.x;
    const int tx = tid & 15, ty = tid >> 4;

    // State pointers
    const float* h_below = (l == 0) ? (hemb + (size_t)t * D * B)
                                    : (hpp + ((size_t)(p ^ 1) * 8 + (l - 1)) * D * B);
    const float* h_prev  = (l == 8) ? (hfinal + (size_t)(t > 0 ? t - 1 : 0) * D * B)
                                    : (hpp + ((size_t)(p ^ 1) * 8 + l) * D * B);
    const float* c_old = cpp + ((size_t)(p ^ 1) * 9 + l) * D * B;
    float*       c_new = cpp + ((size_t)p * 9 + l) * D * B;
    float*       h_out = (l == 8) ? (hfinal + (size_t)t * D * B)
                                  : (hpp + ((size_t)p * 8 + l) * D * B);

    const float* Wl_ih = W_ih + (size_t)l * G * D;
    const float* Wl_hh = W_hh + (size_t)l * G * D;
    const float* bl    = bias + (size_t)l * G;

    __shared__ float As[32][68];  // [k][b]
    __shared__ float Bs[32][68];  // [k][rr]
    float acc[4][4] = {};         // [b-sub][rr-sub: gate]

    const int nph = (t > 0) ? 2 : 1;
    for (int ph = 0; ph < nph; ph++) {
        const float* A = (ph == 0) ? h_below : h_prev;
        const float* W = (ph == 0) ? Wl_ih : Wl_hh;
        for (int k0 = 0; k0 < D; k0 += 32) {
            // A tile: 32 k-rows x 64 b, coalesced float4 along b
            {
                int kk = tid >> 4, f4 = tid & 15;
                float4 a0 = *((const float4*)(A + (size_t)(k0 + kk) * B) + f4);
                *(float4*)&As[kk][f4 * 4] = a0;
                float4 a1 = *((const float4*)(A + (size_t)(k0 + kk + 16) * B) + f4);
                *(float4*)&As[kk + 16][f4 * 4] = a1;
            }
            // W tile: 64 rows (4 gates x 16 d), k0..k0+31, transposed to Bs[k][rr]
            {
                int nn = tid >> 3, f4k = tid & 7;
#pragma unroll
                for (int h2 = 0; h2 < 2; h2++) {
                    int rr = nn + h2 * 32;
                    int row = (rr & 3) * 512 + d0 + (rr >> 2);
                    float4 w = *((const float4*)(W + (size_t)row * D + k0) + f4k);
                    Bs[f4k * 4 + 0][rr] = w.x;
                    Bs[f4k * 4 + 1][rr] = w.y;
                    Bs[f4k * 4 + 2][rr] = w.z;
                    Bs[f4k * 4 + 3][rr] = w.w;
                }
            }
            __syncthreads();
#pragma unroll
            for (int k = 0; k < 32; k++) {
                float4 a  = *(float4*)&As[k][ty * 4];
                float4 bb = *(float4*)&Bs[k][tx * 4];
                float av[4] = {a.x, a.y, a.z, a.w};
                float bv[4] = {bb.x, bb.y, bb.z, bb.w};
#pragma unroll
                for (int i = 0; i < 4; i++)
#pragma unroll
                    for (int j = 0; j < 4; j++) acc[i][j] = fmaf(av[i], bv[j], acc[i][j]);
            }
            __syncthreads();
        }
    }

    // Epilogue: thread owns (d = d0+tx, b = ty*4+i, gates j=0..3 -> i,f,g,o)
    const int dd = d0 + tx;
    const float b_i = bl[dd];
    const float b_f = bl[512 + dd];
    const float b_g = bl[1024 + dd];
    const float b_o = bl[1536 + dd];
#pragma unroll
    for (int i = 0; i < 4; i++) {
        int bb = ty * 4 + i;
        float gi = acc[i][0] + b_i;
        float gf = acc[i][1] + b_f;
        float gg = acc[i][2] + b_g;
        float go = acc[i][3] + b_o;
        float co = (t > 0) ? c_old[(size_t)dd * B + bb] : 0.f;
        float si = 1.f / (1.f + __expf(-gi));
        float sf = 1.f / (1.f + __expf(-gf));
        float so = 1.f / (1.f + __expf(-go));
        float tg = tanhf(gg);
        float cn = fmaf(sf, co, si * tg);
        c_new[(size_t)dd * B + bb] = cn;
        h_out[(size_t)dd * B + bb] = so * tanhf(cn);
    }
}

// ---------------------------------------------------------------------------
// K4: LayerNorm over D for each (b,t); hfinal is [T][D][B]; hn out is [B][T][D].
// grid = T, block = 256.  Transpose through LDS for coalesced writes.
// ---------------------------------------------------------------------------
__global__ __launch_bounds__(256) void k_ln(const float* __restrict__ h,
                                            const float* __restrict__ gamma,
                                            const float* __restrict__ beta,
                                            float* __restrict__ hn) {
    int t = blockIdx.x;
    int r = threadIdx.x & 63;
    int q = threadIdx.x >> 6;
    const float* ht = h + (size_t)t * D * B;

    __shared__ float red[4][2][64];
    __shared__ float mr[2][64];
    __shared__ float tile[64][65];

    float s1 = 0.f, s2 = 0.f;
    for (int dd = q * 128; dd < q * 128 + 128; dd++) {
        float v = ht[(size_t)dd * B + r];
        s1 += v;
        s2 = fmaf(v, v, s2);
    }
    red[q][0][r] = s1;
    red[q][1][r] = s2;
    __syncthreads();
    if (q == 0) {
        float a = 0.f, b2 = 0.f;
#pragma unroll
        for (int i = 0; i < 4; i++) {
            a += red[i][0][r];
            b2 += red[i][1][r];
        }
        float mean = a / D;
        float var  = b2 / D - mean * mean;
        mr[0][r] = mean;
        mr[1][r] = rsqrtf(var + 1e-5f);
    }
    __syncthreads();

    for (int c0 = 0; c0 < D; c0 += 64) {
#pragma unroll
        for (int j = 0; j < 16; j++) {
            int dl = q * 16 + j;
            int dd = c0 + dl;
            float v = ht[(size_t)dd * B + r];
            v = fmaf((v - mr[0][r]) * mr[1][r], gamma[dd], beta[dd]);
            tile[r][dl] = v;
        }
        __syncthreads();
#pragma unroll
        for (int j = 0; j < 16; j++) {
            int rl = q * 16 + j;  // batch row
            hn[((size_t)rl * T + t) * D + c0 + r] = tile[rl][r];
        }
        __syncthreads();
    }
}

// ---------------------------------------------------------------------------
// K5: head GEMM  logits[m][s] = sum_k hn[m][k]*head_W[s][k] + head_b[s]
// hn row-major [8192][512]; tile 64m x 64s, BK=32. grid = 8192/64 = 128.
// ---------------------------------------------------------------------------
__global__ __launch_bounds__(256) void k_head(const float* __restrict__ hn,
                                              const float* __restrict__ hw,
                                              const float* __restrict__ hb,
                                              float* __restrict__ out) {
    int m0 = blockIdx.x * 64;
    int tid = threadIdx.x;
    int tx = tid & 15, ty = tid >> 4;  // tx: s-sub, ty: m-sub

    __shared__ float As[32][68];  // [k][m]
    __shared__ float Bs[32][68];  // [k][s]
    float acc[4][4] = {};         // [m][s]

    for (int k0 = 0; k0 < D; k0 += 32) {
        int mm = tid >> 3, f4k = tid & 7;
#pragma unroll
        for (int h2 = 0; h2 < 2; h2++) {
            int m = mm + h2 * 32;
            float4 a = *((const float4*)(hn + (size_t)(m0 + m) * D + k0) + f4k);
            As[f4k * 4 + 0][m] = a.x;
            As[f4k * 4 + 1][m] = a.y;
            As[f4k * 4 + 2][m] = a.z;
            As[f4k * 4 + 3][m] = a.w;
            float4 w = *((const float4*)(hw + (size_t)m * D + k0) + f4k);  // m doubles as s row
            Bs[f4k * 4 + 0][m] = w.x;
            Bs[f4k * 4 + 1][m] = w.y;
            Bs[f4k * 4 + 2][m] = w.z;
            Bs[f4k * 4 + 3][m] = w.w;
        }
        __syncthreads();
#pragma unroll
        for (int k = 0; k < 32; k++) {
            float4 a  = *(float4*)&As[k][ty * 4];
            float4 bb = *(float4*)&Bs[k][tx * 4];
            float av[4] = {a.x, a.y, a.z, a.w};
            float bv[4] = {bb.x, bb.y, bb.z, bb.w};
#pragma unroll
            for (int i = 0; i < 4; i++)
#pragma unroll
                for (int j = 0; j < 4; j++) acc[i][j] = fmaf(av[i], bv[j], acc[i][j]);
        }
        __syncthreads();
    }
    float* o = out + (size_t)m0 * S;
#pragma unroll
    for (int i = 0; i < 4; i++) {
        int m = ty * 4 + i;
        float4 v;
        v.x = acc[i][0] + hb[tx * 4 + 0];
        v.y = acc[i][1] + hb[tx * 4 + 1];
        v.z = acc[i][2] + hb[tx * 4 + 2];
        v.w = acc[i][3] + hb[tx * 4 + 3];
        *(float4*)(o + (size_t)m * S + tx * 4) = v;
    }
}

// ---------------------------------------------------------------------------
extern "C" void kernel_launch(void* const* d_in, const int* in_sizes, int n_in,
                              void* d_out, int out_size, void* d_ws, size_t ws_size,
                              hipStream_t stream) {
    const int*   x      = (const int*)d_in[0];
    const float* emb    = (const float*)d_in[1];
    const float* W_ih   = (const float*)d_in[2];
    const float* W_hh   = (const float*)d_in[3];
    const float* bvec   = (const float*)d_in[4];
    const float* gamma  = (const float*)d_in[5];
    const float* beta   = (const float*)d_in[6];
    const float* head_W = (const float*)d_in[7];
    const float* head_b = (const float*)d_in[8];

    float* logits = (float*)d_out;                      // [B,T,S]
    float* hn     = (float*)d_out + (size_t)B * T * S;  // [B,T,D]

    float* hemb   = (float*)d_ws;                       // [T][D][B]
    float* hfinal = hemb + (size_t)T * D * B;           // [T][D][B]
    float* hpp    = hfinal + (size_t)T * D * B;         // [2][8][D][B]
    float* cpp    = hpp + (size_t)2 * 8 * D * B;        // [2][9][D][B]

    k_embed<<<dim3(T * 8), 256, 0, stream>>>(x, emb, hemb);

    for (int d = 0; d <= (L - 1) + (T - 1); d++) {
        int lmin = (d > T - 1) ? (d - (T - 1)) : 0;
        int lmax = (d < L - 1) ? d : (L - 1);
        int ncells = lmax - lmin + 1;
        k_cell<<<dim3(ncells * 32), 256, 0, stream>>>(hemb, hfinal, hpp, cpp,
                                                      W_ih, W_hh, bvec, d);
    }

    k_ln<<<dim3(T), 256, 0, stream>>>(hfinal, gamma, beta, hn);
    k_head<<<dim3(B * T / 64), 256, 0, stream>>>(hn, head_W, head_b, logits);
}

// Round 3
// 2420.061 us; speedup vs baseline: 9.7716x; 3.3292x over previous
//
#include <hip/hip_runtime.h>
#include <hip/hip_bf16.h>
#include <math.h>

// Problem constants
constexpr int B = 64, T = 128, D = 512, L = 9, S = 64;
constexpr int G = 4 * D;  // 2048 gate rows per layer

typedef __attribute__((ext_vector_type(8))) short short8;  // 8 bf16 = 4 VGPR
typedef __attribute__((ext_vector_type(4))) float f32x4;

// ---------------------------------------------------------------------------
// Workspace layout (bytes):
//  Wpk  [L][2048][1024] bf16   rows remapped rr=4*d+gate, k<512=W_ih, k>=512=W_hh
//  bpk  [L][2048] f32          same row remap
//  hemb [T][B][D] bf16
//  hpp  [2][L][B][D] bf16      parity ping-pong h state (incl. layer 8)
//  cpp  [2][L][B][D] f32       parity ping-pong c state
//  hfin [T][B][D] f32          layer-8 h history (feeds LayerNorm)
// ---------------------------------------------------------------------------
constexpr size_t WPK_BYTES  = (size_t)L * 2048 * 1024 * 2;   // 37,748,736
constexpr size_t BPK_BYTES  = (size_t)L * 2048 * 4;          // 73,728
constexpr size_t HEMB_BYTES = (size_t)T * B * D * 2;         // 8,388,608
constexpr size_t HPP_BYTES  = (size_t)2 * L * B * D * 2;     // 1,179,648
constexpr size_t CPP_BYTES  = (size_t)2 * L * B * D * 4;     // 2,359,296

// ---------------------------------------------------------------------------
// K0: pack weights+bias to bf16, fused [ih|hh] K-space, remapped rows.
// grid = L*2048 (one block per packed row), block = 256 (4 k each)
// ---------------------------------------------------------------------------
__global__ __launch_bounds__(256) void k_pack(const float* __restrict__ W_ih,
                                              const float* __restrict__ W_hh,
                                              const float* __restrict__ bsrc,
                                              unsigned short* __restrict__ Wpk,
                                              float* __restrict__ bpk) {
    int rr = blockIdx.x;
    int l  = rr >> 11;
    int rl = rr & 2047;
    int g  = rl & 3, dd = rl >> 2;
    int srow = g * D + dd;  // source row within layer (gate-major)
    int k = threadIdx.x * 4;
    const float* src = (k < D) ? (W_ih + ((size_t)l * G + srow) * D + k)
                               : (W_hh + ((size_t)l * G + srow) * D + (k - D));
    float4 v = *(const float4*)src;
    __hip_bfloat16 b0 = __float2bfloat16(v.x), b1 = __float2bfloat16(v.y),
                   b2 = __float2bfloat16(v.z), b3 = __float2bfloat16(v.w);
    ushort4 pk;
    pk.x = *(unsigned short*)&b0; pk.y = *(unsigned short*)&b1;
    pk.z = *(unsigned short*)&b2; pk.w = *(unsigned short*)&b3;
    *(ushort4*)(Wpk + ((size_t)l * 2048 + rl) * 1024 + k) = pk;
    if (threadIdx.x == 0) bpk[(size_t)l * 2048 + rl] = bsrc[(size_t)l * G + srow];
}

// ---------------------------------------------------------------------------
// K1: embedding gather -> hemb [t][b][d] bf16.  grid = T*B/2, block 256.
// ---------------------------------------------------------------------------
__global__ __launch_bounds__(256) void k_embed(const int* __restrict__ x,
                                               const float* __restrict__ emb,
                                               unsigned short* __restrict__ hemb) {
    int row = blockIdx.x * 2 + (threadIdx.x >> 7);  // row = t*B + b
    int t = row >> 6, b = row & 63;
    int d0 = (threadIdx.x & 127) * 4;
    int xi = x[b * T + t];
    float4 v = *(const float4*)(emb + (size_t)xi * D + d0);
    __hip_bfloat16 b0 = __float2bfloat16(v.x), b1 = __float2bfloat16(v.y),
                   b2 = __float2bfloat16(v.z), b3 = __float2bfloat16(v.w);
    ushort4 pk;
    pk.x = *(unsigned short*)&b0; pk.y = *(unsigned short*)&b1;
    pk.z = *(unsigned short*)&b2; pk.w = *(unsigned short*)&b3;
    *(ushort4*)(hemb + (size_t)row * D + d0) = pk;
}

// ---------------------------------------------------------------------------
// K2: one wavefront-diagonal of LSTM cells, MFMA bf16.
// Cell (l,t), l+t==d.  Block bt of 32 covers wrows [bt*64, bt*64+64) x 64 b.
// Wave w owns 16 wrows; out C[row=batch][col=wrow] via mfma(h_frag, w_frag).
// Each lane: col = wrow = r0+w*16+(lane&15) -> (d = wrow>>2, gate = wrow&3);
// 4x4 lane/reg shfl-transpose regroups so lane holds all 4 gates of one (d,b).
// Staging: depth-4 ring of global_load_lds (16B), counted vmcnt(4).
// ---------------------------------------------------------------------------
__global__ __launch_bounds__(256) void k_cell(const unsigned short* __restrict__ Wpk,
                                              const float* __restrict__ bpk,
                                              const unsigned short* __restrict__ hemb,
                                              unsigned short* __restrict__ hpp,
                                              float* __restrict__ cpp,
                                              float* __restrict__ hfin,
                                              int d) {
    const int lmin = (d > T - 1) ? (d - (T - 1)) : 0;
    const int l  = lmin + (blockIdx.x >> 5);
    const int bt = blockIdx.x & 31;
    const int t  = d - l;
    const int p  = d & 1;
    const int r0 = bt * 64;

    const int tid  = threadIdx.x;
    const int w    = tid >> 6;   // wave 0..3
    const int lane = tid & 63;

    __shared__ unsigned short Wt[4][64][32];  // ring buffers: [buf][wrow][k]
    __shared__ unsigned short Ht[4][64][32];  //               [buf][b][k]

    const unsigned short* Wl = Wpk + (size_t)l * 2048 * 1024;
    const unsigned short* hb = (l == 0) ? (hemb + (size_t)t * B * D)
                                        : (hpp + ((size_t)(p ^ 1) * L + (l - 1)) * B * D);
    const unsigned short* hp = hpp + ((size_t)(p ^ 1) * L + l) * B * D;
    const float* c_old = cpp + ((size_t)(p ^ 1) * L + l) * B * D;
    float*       c_new = cpp + ((size_t)p * L + l) * B * D;
    unsigned short* h_out = hpp + ((size_t)p * L + l) * B * D;

    const int nsteps = (t > 0) ? 32 : 16;  // K = 1024 (ih+hh) or 512 (ih only)

    const int srow_w = r0 + w * 16 + (lane >> 2);   // W staging row for this lane
    const int hrow_w = w * 16 + (lane >> 2);        // h staging row (= batch)
    const int lk16   = (lane & 3) * 8;              // 8 bf16 = 16B chunk within row

    auto stage = [&](int step) {
        int k0  = step * 32;
        int buf = step & 3;
        const unsigned short* wsrc = Wl + (size_t)srow_w * 1024 + k0 + lk16;
        __builtin_amdgcn_global_load_lds(
            (const __attribute__((address_space(1))) unsigned int*)wsrc,
            (__attribute__((address_space(3))) unsigned int*)&Wt[buf][w * 16][0],
            16, 0, 0);
        const unsigned short* hbase = (k0 < D) ? hb : hp;
        const unsigned short* hsrc = hbase + (size_t)hrow_w * D + (k0 & (D - 1)) + lk16;
        __builtin_amdgcn_global_load_lds(
            (const __attribute__((address_space(1))) unsigned int*)hsrc,
            (__attribute__((address_space(3))) unsigned int*)&Ht[buf][w * 16][0],
            16, 0, 0);
    };

    f32x4 acc[4] = {{0.f, 0.f, 0.f, 0.f}, {0.f, 0.f, 0.f, 0.f},
                    {0.f, 0.f, 0.f, 0.f}, {0.f, 0.f, 0.f, 0.f}};
    const int fr = lane & 15;  // fragment row index
    const int fq = lane >> 4;  // quarter

    auto compute = [&](int step) {
        int buf = step & 3;
        short8 wf = *(const short8*)&Wt[buf][w * 16 + fr][fq * 8];
#pragma unroll
        for (int rt = 0; rt < 4; rt++) {
            short8 hf = *(const short8*)&Ht[buf][rt * 16 + fr][fq * 8];
            acc[rt] = __builtin_amdgcn_mfma_f32_16x16x32_bf16(hf, wf, acc[rt], 0, 0, 0);
        }
    };

    stage(0); stage(1); stage(2);
    for (int i = 0; i < nsteps - 3; ++i) {
        asm volatile("s_waitcnt vmcnt(4)" ::: "memory");
        __builtin_amdgcn_s_barrier();
        __builtin_amdgcn_sched_barrier(0);
        stage(i + 3);
        compute(i);
    }
    asm volatile("s_waitcnt vmcnt(4)" ::: "memory");
    __builtin_amdgcn_s_barrier();
    __builtin_amdgcn_sched_barrier(0);
    compute(nsteps - 3);
    asm volatile("s_waitcnt vmcnt(2)" ::: "memory");
    __builtin_amdgcn_s_barrier();
    __builtin_amdgcn_sched_barrier(0);
    compute(nsteps - 2);
    asm volatile("s_waitcnt vmcnt(0)" ::: "memory");
    __builtin_amdgcn_s_barrier();
    __builtin_amdgcn_sched_barrier(0);
    compute(nsteps - 1);

    // ---- Epilogue: lane owns wrow = r0 + w*16 + fr  ->  d = wrow>>2 ----
    const int wrow = r0 + w * 16 + fr;
    const int dd   = wrow >> 2;
    const float4 bias4 = *(const float4*)&bpk[(size_t)l * 2048 + (dd << 2)];  // i,f,g,o

#pragma unroll
    for (int rt = 0; rt < 4; rt++) {
        float v0 = acc[rt].x, v1 = acc[rt].y, v2 = acc[rt].z, v3 = acc[rt].w;
        // 4x4 lane/reg transpose within 4-lane group (lanes = gates -> lanes = batches)
        float s0 = __shfl_xor(v0, 1), s1 = __shfl_xor(v1, 1),
              s2 = __shfl_xor(v2, 1), s3 = __shfl_xor(v3, 1);
        bool o1 = (lane & 1) != 0;
        float p0 = o1 ? s1 : v0;
        float p1 = o1 ? v1 : s0;
        float p2 = o1 ? s3 : v2;
        float p3 = o1 ? v3 : s2;
        float q0 = __shfl_xor(p0, 2), q1 = __shfl_xor(p1, 2),
              q2 = __shfl_xor(p2, 2), q3 = __shfl_xor(p3, 2);
        bool o2 = (lane & 2) != 0;
        float gi = (o2 ? q2 : p0) + bias4.x;
        float gf = (o2 ? q3 : p1) + bias4.y;
        float gg = (o2 ? p2 : q0) + bias4.z;
        float go = (o2 ? p3 : q1) + bias4.w;

        int bb = rt * 16 + fq * 4 + (lane & 3);
        float co = 0.f;
        if (t > 0) co = c_old[(size_t)bb * D + dd];
        float si = 1.f / (1.f + __expf(-gi));
        float sf = 1.f / (1.f + __expf(-gf));
        float so = 1.f / (1.f + __expf(-go));
        float tg = tanhf(gg);
        float cn = fmaf(sf, co, si * tg);
        float hv = so * tanhf(cn);
        c_new[(size_t)bb * D + dd] = cn;
        __hip_bfloat16 hvb = __float2bfloat16(hv);
        h_out[(size_t)bb * D + dd] = *(unsigned short*)&hvb;
        if (l == 8) hfin[((size_t)t * B + bb) * D + dd] = hv;
    }
}

// ---------------------------------------------------------------------------
// K3: LayerNorm.  hfin [t*B+b][D] f32 -> hn [b*T+t][D] f32.  1 wave per row.
// grid = B*T/4, block 256.
// ---------------------------------------------------------------------------
__global__ __launch_bounds__(256) void k_ln(const float* __restrict__ hfin,
                                            const float* __restrict__ gamma,
                                            const float* __restrict__ beta,
                                            float* __restrict__ hn) {
    int row  = blockIdx.x * 4 + (threadIdx.x >> 6);  // t*B + b
    int lane = threadIdx.x & 63;
    int t = row >> 6, b = row & 63;
    const float* in = hfin + (size_t)row * D;
    float4 a = *((const float4*)in + lane * 2);
    float4 c = *((const float4*)in + lane * 2 + 1);
    float s1 = a.x + a.y + a.z + a.w + c.x + c.y + c.z + c.w;
    float s2 = a.x * a.x + a.y * a.y + a.z * a.z + a.w * a.w +
               c.x * c.x + c.y * c.y + c.z * c.z + c.w * c.w;
#pragma unroll
    for (int m = 1; m < 64; m <<= 1) {
        s1 += __shfl_xor(s1, m);
        s2 += __shfl_xor(s2, m);
    }
    float mean = s1 / D;
    float rstd = rsqrtf(s2 / D - mean * mean + 1e-5f);
    float4 g0 = *((const float4*)gamma + lane * 2);
    float4 g1 = *((const float4*)gamma + lane * 2 + 1);
    float4 be0 = *((const float4*)beta + lane * 2);
    float4 be1 = *((const float4*)beta + lane * 2 + 1);
    float4 o0, o1;
    o0.x = fmaf((a.x - mean) * rstd, g0.x, be0.x);
    o0.y = fmaf((a.y - mean) * rstd, g0.y, be0.y);
    o0.z = fmaf((a.z - mean) * rstd, g0.z, be0.z);
    o0.w = fmaf((a.w - mean) * rstd, g0.w, be0.w);
    o1.x = fmaf((c.x - mean) * rstd, g1.x, be1.x);
    o1.y = fmaf((c.y - mean) * rstd, g1.y, be1.y);
    o1.z = fmaf((c.z - mean) * rstd, g1.z, be1.z);
    o1.w = fmaf((c.w - mean) * rstd, g1.w, be1.w);
    float* out = hn + ((size_t)b * T + t) * D;
    *((float4*)out + lane * 2) = o0;
    *((float4*)out + lane * 2 + 1) = o1;
}

// ---------------------------------------------------------------------------
// K4: head GEMM  logits[m][s] = sum_k hn[m][k]*head_W[s][k] + head_b[s]
// hn row-major [8192][512]; tile 64m x 64s, BK=32. grid = 128.
// ---------------------------------------------------------------------------
__global__ __launch_bounds__(256) void k_head(const float* __restrict__ hn,
                                              const float* __restrict__ hw,
                                              const float* __restrict__ hb,
                                              float* __restrict__ out) {
    int m0 = blockIdx.x * 64;
    int tid = threadIdx.x;
    int tx = tid & 15, ty = tid >> 4;

    __shared__ float As[32][68];
    __shared__ float Bs[32][68];
    float acc[4][4] = {};

    for (int k0 = 0; k0 < D; k0 += 32) {
        int mm = tid >> 3, f4k = tid & 7;
#pragma unroll
        for (int h2 = 0; h2 < 2; h2++) {
            int m = mm + h2 * 32;
            float4 a = *((const float4*)(hn + (size_t)(m0 + m) * D + k0) + f4k);
            As[f4k * 4 + 0][m] = a.x;
            As[f4k * 4 + 1][m] = a.y;
            As[f4k * 4 + 2][m] = a.z;
            As[f4k * 4 + 3][m] = a.w;
            float4 wv = *((const float4*)(hw + (size_t)m * D + k0) + f4k);
            Bs[f4k * 4 + 0][m] = wv.x;
            Bs[f4k * 4 + 1][m] = wv.y;
            Bs[f4k * 4 + 2][m] = wv.z;
            Bs[f4k * 4 + 3][m] = wv.w;
        }
        __syncthreads();
#pragma unroll
        for (int k = 0; k < 32; k++) {
            float4 a  = *(float4*)&As[k][ty * 4];
            float4 bb = *(float4*)&Bs[k][tx * 4];
            float av[4] = {a.x, a.y, a.z, a.w};
            float bv[4] = {bb.x, bb.y, bb.z, bb.w};
#pragma unroll
            for (int i = 0; i < 4; i++)
#pragma unroll
                for (int j = 0; j < 4; j++) acc[i][j] = fmaf(av[i], bv[j], acc[i][j]);
        }
        __syncthreads();
    }
    float* o = out + (size_t)m0 * S;
#pragma unroll
    for (int i = 0; i < 4; i++) {
        int m = ty * 4 + i;
        float4 v;
        v.x = acc[i][0] + hb[tx * 4 + 0];
        v.y = acc[i][1] + hb[tx * 4 + 1];
        v.z = acc[i][2] + hb[tx * 4 + 2];
        v.w = acc[i][3] + hb[tx * 4 + 3];
        *(float4*)(o + (size_t)m * S + tx * 4) = v;
    }
}

// ---------------------------------------------------------------------------
extern "C" void kernel_launch(void* const* d_in, const int* in_sizes, int n_in,
                              void* d_out, int out_size, void* d_ws, size_t ws_size,
                              hipStream_t stream) {
    const int*   x      = (const int*)d_in[0];
    const float* emb    = (const float*)d_in[1];
    const float* W_ih   = (const float*)d_in[2];
    const float* W_hh   = (const float*)d_in[3];
    const float* bvec   = (const float*)d_in[4];
    const float* gamma  = (const float*)d_in[5];
    const float* beta   = (const float*)d_in[6];
    const float* head_W = (const float*)d_in[7];
    const float* head_b = (const float*)d_in[8];

    float* logits = (float*)d_out;                      // [B,T,S]
    float* hn     = (float*)d_out + (size_t)B * T * S;  // [B,T,D]

    char* ws = (char*)d_ws;
    unsigned short* Wpk  = (unsigned short*)ws;
    float*          bpk  = (float*)(ws + WPK_BYTES);
    unsigned short* hemb = (unsigned short*)(ws + WPK_BYTES + BPK_BYTES);
    unsigned short* hpp  = (unsigned short*)(ws + WPK_BYTES + BPK_BYTES + HEMB_BYTES);
    float*          cpp  = (float*)(ws + WPK_BYTES + BPK_BYTES + HEMB_BYTES + HPP_BYTES);
    float*          hfin = (float*)(ws + WPK_BYTES + BPK_BYTES + HEMB_BYTES + HPP_BYTES + CPP_BYTES);

    k_pack<<<dim3(L * 2048), 256, 0, stream>>>(W_ih, W_hh, bvec, Wpk, bpk);
    k_embed<<<dim3(T * B / 2), 256, 0, stream>>>(x, emb, hemb);

    for (int d = 0; d <= (L - 1) + (T - 1); d++) {
        int lmin = (d > T - 1) ? (d - (T - 1)) : 0;
        int lmax = (d < L - 1) ? d : (L - 1);
        int ncells = lmax - lmin + 1;
        k_cell<<<dim3(ncells * 32), 256, 0, stream>>>(Wpk, bpk, hemb, hpp, cpp, hfin, d);
    }

    k_ln<<<dim3(B * T / 4), 256, 0, stream>>>(hfin, gamma, beta, hn);
    k_head<<<dim3(B * T / 64), 256, 0, stream>>>(hn, head_W, head_b, logits);
}

// Round 4
// 2010.264 us; speedup vs baseline: 11.7636x; 1.2039x over previous
//
#include <hip/hip_runtime.h>
#include <hip/hip_bf16.h>
#include <math.h>

// Problem constants
constexpr int B = 64, T = 128, D = 512, L = 9, S = 64;
constexpr int G = 4 * D;  // 2048 gate rows per layer

typedef __attribute__((ext_vector_type(8))) short short8;  // 8 bf16 = 4 VGPR
typedef __attribute__((ext_vector_type(4))) float f32x4;

// ---------------------------------------------------------------------------
// Workspace layout (bytes):
//  Wpk  [L][2048][1024] bf16   rows remapped rr=4*d+gate, k<512=W_ih, k>=512=W_hh
//  bpk  [L][2048] f32          same row remap
//  hemb [T][B][D] bf16
//  hpp  [2][L][B][D] bf16      parity ping-pong h state (incl. layer 8)
//  cpp  [2][L][B][D] f32       parity ping-pong c state
//  hfin [T][B][D] f32          layer-8 h history (feeds LayerNorm)
// ---------------------------------------------------------------------------
constexpr size_t WPK_BYTES  = (size_t)L * 2048 * 1024 * 2;   // 37,748,736
constexpr size_t BPK_BYTES  = (size_t)L * 2048 * 4;          // 73,728
constexpr size_t HEMB_BYTES = (size_t)T * B * D * 2;         // 8,388,608
constexpr size_t HPP_BYTES  = (size_t)2 * L * B * D * 2;     // 1,179,648
constexpr size_t CPP_BYTES  = (size_t)2 * L * B * D * 4;     // 2,359,296

// ---------------------------------------------------------------------------
// K0: pack weights+bias to bf16, fused [ih|hh] K-space, remapped rows.
// grid = L*2048 (one block per packed row), block = 256 (4 k each)
// ---------------------------------------------------------------------------
__global__ __launch_bounds__(256) void k_pack(const float* __restrict__ W_ih,
                                              const float* __restrict__ W_hh,
                                              const float* __restrict__ bsrc,
                                              unsigned short* __restrict__ Wpk,
                                              float* __restrict__ bpk) {
    int rr = blockIdx.x;
    int l  = rr >> 11;
    int rl = rr & 2047;
    int g  = rl & 3, dd = rl >> 2;
    int srow = g * D + dd;  // source row within layer (gate-major)
    int k = threadIdx.x * 4;
    const float* src = (k < D) ? (W_ih + ((size_t)l * G + srow) * D + k)
                               : (W_hh + ((size_t)l * G + srow) * D + (k - D));
    float4 v = *(const float4*)src;
    __hip_bfloat16 b0 = __float2bfloat16(v.x), b1 = __float2bfloat16(v.y),
                   b2 = __float2bfloat16(v.z), b3 = __float2bfloat16(v.w);
    ushort4 pk;
    pk.x = *(unsigned short*)&b0; pk.y = *(unsigned short*)&b1;
    pk.z = *(unsigned short*)&b2; pk.w = *(unsigned short*)&b3;
    *(ushort4*)(Wpk + ((size_t)l * 2048 + rl) * 1024 + k) = pk;
    if (threadIdx.x == 0) bpk[(size_t)l * 2048 + rl] = bsrc[(size_t)l * G + srow];
}

// ---------------------------------------------------------------------------
// K1: embedding gather -> hemb [t][b][d] bf16.  grid = T*B/2, block 256.
// ---------------------------------------------------------------------------
__global__ __launch_bounds__(256) void k_embed(const int* __restrict__ x,
                                               const float* __restrict__ emb,
                                               unsigned short* __restrict__ hemb) {
    int row = blockIdx.x * 2 + (threadIdx.x >> 7);  // row = t*B + b
    int t = row >> 6, b = row & 63;
    int d0 = (threadIdx.x & 127) * 4;
    int xi = x[b * T + t];
    float4 v = *(const float4*)(emb + (size_t)xi * D + d0);
    __hip_bfloat16 b0 = __float2bfloat16(v.x), b1 = __float2bfloat16(v.y),
                   b2 = __float2bfloat16(v.z), b3 = __float2bfloat16(v.w);
    ushort4 pk;
    pk.x = *(unsigned short*)&b0; pk.y = *(unsigned short*)&b1;
    pk.z = *(unsigned short*)&b2; pk.w = *(unsigned short*)&b3;
    *(ushort4*)(hemb + (size_t)row * D + d0) = pk;
}

// ---------------------------------------------------------------------------
// K2: one wavefront-diagonal of LSTM cells, MFMA bf16.
// Cell (l,t), l+t==d.  Block bt of 32 covers wrows [bt*64, bt*64+64) x 64 b.
// Wave w owns 16 wrows; C[row=batch][col=wrow] via mfma(h_frag, w_frag).
// BK=64 per step (nsteps = 16 / 8), depth-4 LDS ring (64 KB -> 2 blocks/CU),
// counted vmcnt(8) so staged loads stay in flight across 3 steps (T4).
// LDS tiles XOR-swizzled (elem ^= (row&7)<<3) to kill ds_read_b128 bank
// conflicts (T2); global_load_lds forces linear dest, so the *global source*
// is inverse-permuted instead (rule #21).
// ---------------------------------------------------------------------------
__global__ __launch_bounds__(256) void k_cell(const unsigned short* __restrict__ Wpk,
                                              const float* __restrict__ bpk,
                                              const unsigned short* __restrict__ hemb,
                                              unsigned short* __restrict__ hpp,
                                              float* __restrict__ cpp,
                                              float* __restrict__ hfin,
                                              int d) {
    const int lmin = (d > T - 1) ? (d - (T - 1)) : 0;
    const int l  = lmin + (blockIdx.x >> 5);
    const int bt = blockIdx.x & 31;
    const int t  = d - l;
    const int p  = d & 1;
    const int r0 = bt * 64;

    const int tid  = threadIdx.x;
    const int w    = tid >> 6;   // wave 0..3
    const int lane = tid & 63;

    __shared__ unsigned short Wt[4][64][64];  // ring: [buf][wrow][k]  (8 KB/buf)
    __shared__ unsigned short Ht[4][64][64];  //       [buf][b][k]

    const unsigned short* Wl = Wpk + (size_t)l * 2048 * 1024;
    const unsigned short* hb = (l == 0) ? (hemb + (size_t)t * B * D)
                                        : (hpp + ((size_t)(p ^ 1) * L + (l - 1)) * B * D);
    const unsigned short* hp = hpp + ((size_t)(p ^ 1) * L + l) * B * D;
    const float* c_old = cpp + ((size_t)(p ^ 1) * L + l) * B * D;
    float*       c_new = cpp + ((size_t)p * L + l) * B * D;
    unsigned short* h_out = hpp + ((size_t)p * L + l) * B * D;

    const int nsteps = (t > 0) ? 16 : 8;  // K = 1024 (ih+hh) or 512 (ih only)

    // Staging lane decomposition: 8 rows x 8 chunks of 16B per 1KB call.
    const int sr   = lane >> 3;          // row-in-8
    const int sc   = lane & 7;           // 16B chunk
    const int kswz = ((sc ^ sr) << 3);   // inverse-swizzled element offset in row

    auto stage = [&](int step) {
        int k0  = step * 64;
        int buf = step & 3;
#pragma unroll
        for (int c = 0; c < 2; c++) {
            int row = r0 + w * 16 + c * 8 + sr;
            const unsigned short* wsrc = Wl + (size_t)row * 1024 + k0 + kswz;
            __builtin_amdgcn_global_load_lds(
                (const __attribute__((address_space(1))) unsigned int*)wsrc,
                (__attribute__((address_space(3))) unsigned int*)&Wt[buf][w * 16 + c * 8][0],
                16, 0, 0);
        }
        const unsigned short* hbase = (k0 < D) ? hb : hp;
        const int kk = (k0 & (D - 1)) + kswz;
#pragma unroll
        for (int c = 0; c < 2; c++) {
            int bb = w * 16 + c * 8 + sr;
            const unsigned short* hsrc = hbase + (size_t)bb * D + kk;
            __builtin_amdgcn_global_load_lds(
                (const __attribute__((address_space(1))) unsigned int*)hsrc,
                (__attribute__((address_space(3))) unsigned int*)&Ht[buf][w * 16 + c * 8][0],
                16, 0, 0);
        }
    };

    f32x4 acc[4] = {{0.f, 0.f, 0.f, 0.f}, {0.f, 0.f, 0.f, 0.f},
                    {0.f, 0.f, 0.f, 0.f}, {0.f, 0.f, 0.f, 0.f}};
    const int fr = lane & 15;  // fragment row index
    const int fq = lane >> 4;  // quarter
    const int cswz = (fr & 7) << 3;

    auto compute = [&](int step) {
        int buf = step & 3;
#pragma unroll
        for (int kc = 0; kc < 2; kc++) {
            int col = (kc * 32 + fq * 8) ^ cswz;
            short8 wf = *(const short8*)&Wt[buf][w * 16 + fr][col];
#pragma unroll
            for (int rt = 0; rt < 4; rt++) {
                short8 hf = *(const short8*)&Ht[buf][rt * 16 + fr][col];
                acc[rt] = __builtin_amdgcn_mfma_f32_16x16x32_bf16(hf, wf, acc[rt], 0, 0, 0);
            }
        }
    };

    stage(0); stage(1); stage(2);
    for (int i = 0; i < nsteps - 3; ++i) {
        asm volatile("s_waitcnt vmcnt(8)" ::: "memory");
        __builtin_amdgcn_s_barrier();
        __builtin_amdgcn_sched_barrier(0);
        stage(i + 3);
        compute(i);
    }
    asm volatile("s_waitcnt vmcnt(8)" ::: "memory");
    __builtin_amdgcn_s_barrier();
    __builtin_amdgcn_sched_barrier(0);
    compute(nsteps - 3);
    asm volatile("s_waitcnt vmcnt(4)" ::: "memory");
    __builtin_amdgcn_s_barrier();
    __builtin_amdgcn_sched_barrier(0);
    compute(nsteps - 2);
    asm volatile("s_waitcnt vmcnt(0)" ::: "memory");
    __builtin_amdgcn_s_barrier();
    __builtin_amdgcn_sched_barrier(0);
    compute(nsteps - 1);

    // ---- Epilogue: lane owns wrow = r0 + w*16 + fr  ->  d = wrow>>2 ----
    const int wrow = r0 + w * 16 + fr;
    const int dd   = wrow >> 2;
    const float4 bias4 = *(const float4*)&bpk[(size_t)l * 2048 + (dd << 2)];  // i,f,g,o

#pragma unroll
    for (int rt = 0; rt < 4; rt++) {
        float v0 = acc[rt].x, v1 = acc[rt].y, v2 = acc[rt].z, v3 = acc[rt].w;
        // 4x4 lane/reg transpose within 4-lane group (lanes = gates -> lanes = batches)
        float s0 = __shfl_xor(v0, 1), s1 = __shfl_xor(v1, 1),
              s2 = __shfl_xor(v2, 1), s3 = __shfl_xor(v3, 1);
        bool o1 = (lane & 1) != 0;
        float p0 = o1 ? s1 : v0;
        float p1 = o1 ? v1 : s0;
        float p2 = o1 ? s3 : v2;
        float p3 = o1 ? v3 : s2;
        float q0 = __shfl_xor(p0, 2), q1 = __shfl_xor(p1, 2),
              q2 = __shfl_xor(p2, 2), q3 = __shfl_xor(p3, 2);
        bool o2 = (lane & 2) != 0;
        float gi = (o2 ? q2 : p0) + bias4.x;
        float gf = (o2 ? q3 : p1) + bias4.y;
        float gg = (o2 ? p2 : q0) + bias4.z;
        float go = (o2 ? p3 : q1) + bias4.w;

        int bb = rt * 16 + fq * 4 + (lane & 3);
        float co = 0.f;
        if (t > 0) co = c_old[(size_t)bb * D + dd];
        float si = 1.f / (1.f + __expf(-gi));
        float sf = 1.f / (1.f + __expf(-gf));
        float so = 1.f / (1.f + __expf(-go));
        float tg = tanhf(gg);
        float cn = fmaf(sf, co, si * tg);
        float hv = so * tanhf(cn);
        c_new[(size_t)bb * D + dd] = cn;
        __hip_bfloat16 hvb = __float2bfloat16(hv);
        h_out[(size_t)bb * D + dd] = *(unsigned short*)&hvb;
        if (l == 8) hfin[((size_t)t * B + bb) * D + dd] = hv;
    }
}

// ---------------------------------------------------------------------------
// K3: LayerNorm.  hfin [t*B+b][D] f32 -> hn [b*T+t][D] f32.  1 wave per row.
// grid = B*T/4, block 256.
// ---------------------------------------------------------------------------
__global__ __launch_bounds__(256) void k_ln(const float* __restrict__ hfin,
                                            const float* __restrict__ gamma,
                                            const float* __restrict__ beta,
                                            float* __restrict__ hn) {
    int row  = blockIdx.x * 4 + (threadIdx.x >> 6);  // t*B + b
    int lane = threadIdx.x & 63;
    int t = row >> 6, b = row & 63;
    const float* in = hfin + (size_t)row * D;
    float4 a = *((const float4*)in + lane * 2);
    float4 c = *((const float4*)in + lane * 2 + 1);
    float s1 = a.x + a.y + a.z + a.w + c.x + c.y + c.z + c.w;
    float s2 = a.x * a.x + a.y * a.y + a.z * a.z + a.w * a.w +
               c.x * c.x + c.y * c.y + c.z * c.z + c.w * c.w;
#pragma unroll
    for (int m = 1; m < 64; m <<= 1) {
        s1 += __shfl_xor(s1, m);
        s2 += __shfl_xor(s2, m);
    }
    float mean = s1 / D;
    float rstd = rsqrtf(s2 / D - mean * mean + 1e-5f);
    float4 g0 = *((const float4*)gamma + lane * 2);
    float4 g1 = *((const float4*)gamma + lane * 2 + 1);
    float4 be0 = *((const float4*)beta + lane * 2);
    float4 be1 = *((const float4*)beta + lane * 2 + 1);
    float4 o0, o1;
    o0.x = fmaf((a.x - mean) * rstd, g0.x, be0.x);
    o0.y = fmaf((a.y - mean) * rstd, g0.y, be0.y);
    o0.z = fmaf((a.z - mean) * rstd, g0.z, be0.z);
    o0.w = fmaf((a.w - mean) * rstd, g0.w, be0.w);
    o1.x = fmaf((c.x - mean) * rstd, g1.x, be1.x);
    o1.y = fmaf((c.y - mean) * rstd, g1.y, be1.y);
    o1.z = fmaf((c.z - mean) * rstd, g1.z, be1.z);
    o1.w = fmaf((c.w - mean) * rstd, g1.w, be1.w);
    float* out = hn + ((size_t)b * T + t) * D;
    *((float4*)out + lane * 2) = o0;
    *((float4*)out + lane * 2 + 1) = o1;
}

// ---------------------------------------------------------------------------
// K4: head GEMM  logits[m][s] = sum_k hn[m][k]*head_W[s][k] + head_b[s]
// hn row-major [8192][512]; tile 64m x 64s, BK=32. grid = 128.
// ---------------------------------------------------------------------------
__global__ __launch_bounds__(256) void k_head(const float* __restrict__ hn,
                                              const float* __restrict__ hw,
                                              const float* __restrict__ hb,
                                              float* __restrict__ out) {
    int m0 = blockIdx.x * 64;
    int tid = threadIdx.x;
    int tx = tid & 15, ty = tid >> 4;

    __shared__ float As[32][68];
    __shared__ float Bs[32][68];
    float acc[4][4] = {};

    for (int k0 = 0; k0 < D; k0 += 32) {
        int mm = tid >> 3, f4k = tid & 7;
#pragma unroll
        for (int h2 = 0; h2 < 2; h2++) {
            int m = mm + h2 * 32;
            float4 a = *((const float4*)(hn + (size_t)(m0 + m) * D + k0) + f4k);
            As[f4k * 4 + 0][m] = a.x;
            As[f4k * 4 + 1][m] = a.y;
            As[f4k * 4 + 2][m] = a.z;
            As[f4k * 4 + 3][m] = a.w;
            float4 wv = *((const float4*)(hw + (size_t)m * D + k0) + f4k);
            Bs[f4k * 4 + 0][m] = wv.x;
            Bs[f4k * 4 + 1][m] = wv.y;
            Bs[f4k * 4 + 2][m] = wv.z;
            Bs[f4k * 4 + 3][m] = wv.w;
        }
        __syncthreads();
#pragma unroll
        for (int k = 0; k < 32; k++) {
            float4 a  = *(float4*)&As[k][ty * 4];
            float4 bb = *(float4*)&Bs[k][tx * 4];
            float av[4] = {a.x, a.y, a.z, a.w};
            float bv[4] = {bb.x, bb.y, bb.z, bb.w};
#pragma unroll
            for (int i = 0; i < 4; i++)
#pragma unroll
                for (int j = 0; j < 4; j++) acc[i][j] = fmaf(av[i], bv[j], acc[i][j]);
        }
        __syncthreads();
    }
    float* o = out + (size_t)m0 * S;
#pragma unroll
    for (int i = 0; i < 4; i++) {
        int m = ty * 4 + i;
        float4 v;
        v.x = acc[i][0] + hb[tx * 4 + 0];
        v.y = acc[i][1] + hb[tx * 4 + 1];
        v.z = acc[i][2] + hb[tx * 4 + 2];
        v.w = acc[i][3] + hb[tx * 4 + 3];
        *(float4*)(o + (size_t)m * S + tx * 4) = v;
    }
}

// ---------------------------------------------------------------------------
extern "C" void kernel_launch(void* const* d_in, const int* in_sizes, int n_in,
                              void* d_out, int out_size, void* d_ws, size_t ws_size,
                              hipStream_t stream) {
    const int*   x      = (const int*)d_in[0];
    const float* emb    = (const float*)d_in[1];
    const float* W_ih   = (const float*)d_in[2];
    const float* W_hh   = (const float*)d_in[3];
    const float* bvec   = (const float*)d_in[4];
    const float* gamma  = (const float*)d_in[5];
    const float* beta   = (const float*)d_in[6];
    const float* head_W = (const float*)d_in[7];
    const float* head_b = (const float*)d_in[8];

    float* logits = (float*)d_out;                      // [B,T,S]
    float* hn     = (float*)d_out + (size_t)B * T * S;  // [B,T,D]

    char* ws = (char*)d_ws;
    unsigned short* Wpk  = (unsigned short*)ws;
    float*          bpk  = (float*)(ws + WPK_BYTES);
    unsigned short* hemb = (unsigned short*)(ws + WPK_BYTES + BPK_BYTES);
    unsigned short* hpp  = (unsigned short*)(ws + WPK_BYTES + BPK_BYTES + HEMB_BYTES);
    float*          cpp  = (float*)(ws + WPK_BYTES + BPK_BYTES + HEMB_BYTES + HPP_BYTES);
    float*          hfin = (float*)(ws + WPK_BYTES + BPK_BYTES + HEMB_BYTES + HPP_BYTES + CPP_BYTES);

    k_pack<<<dim3(L * 2048), 256, 0, stream>>>(W_ih, W_hh, bvec, Wpk, bpk);
    k_embed<<<dim3(T * B / 2), 256, 0, stream>>>(x, emb, hemb);

    for (int d = 0; d <= (L - 1) + (T - 1); d++) {
        int lmin = (d > T - 1) ? (d - (T - 1)) : 0;
        int lmax = (d < L - 1) ? d : (L - 1);
        int ncells = lmax - lmin + 1;
        k_cell<<<dim3(ncells * 32), 256, 0, stream>>>(Wpk, bpk, hemb, hpp, cpp, hfin, d);
    }

    k_ln<<<dim3(B * T / 4), 256, 0, stream>>>(hfin, gamma, beta, hn);
    k_head<<<dim3(B * T / 64), 256, 0, stream>>>(hn, head_W, head_b, logits);
}